// Round 8
// baseline (263.664 us; speedup 1.0000x reference)
//
#include <hip/hip_runtime.h>
#include <cmath>

// Problem constants (B=1): x (1,4,64,128,128) f32
#define Cc 64
#define Hh 128
#define Ww 128
#define HW_ 16384
#define THW_ 65536
#define CHW_ 1048576
#define NT 27

typedef unsigned short ushort_t;
typedef _Float16 f16x2 __attribute__((ext_vector_type(2)));
typedef _Float16 f16x8 __attribute__((ext_vector_type(8)));
typedef __fp16 fp16x2_alt __attribute__((ext_vector_type(2)));
typedef float floatx4 __attribute__((ext_vector_type(4)));
typedef unsigned uint4v __attribute__((ext_vector_type(4)));

union U32H2 { unsigned u; f16x2 h; };

static __device__ inline ushort_t f2h(float f) {
  union { _Float16 h; ushort_t u; } v;
  v.h = (_Float16)f;
  return v.u;
}

static __device__ inline unsigned pk2(float a) {
  union { fp16x2_alt h; unsigned u; } v;
  v.h = __builtin_amdgcn_cvt_pkrtz(a, a);
  return v.u;
}

// replicate low 16 bits into both halves (weight broadcast for f16x2 math)
static __device__ inline unsigned rep16(unsigned p) {
#if defined(__has_builtin)
#if __has_builtin(__builtin_amdgcn_perm)
  return __builtin_amdgcn_perm(p, p, 0x01000100u);
#else
  return (p & 0xFFFFu) * 0x10001u;
#endif
#else
  return (p & 0xFFFFu) * 0x10001u;
#endif
}

#if defined(__has_builtin)
#if __has_builtin(__builtin_amdgcn_make_buffer_rsrc) && __has_builtin(__builtin_amdgcn_raw_buffer_load_b32) && __has_builtin(__builtin_amdgcn_raw_buffer_load_b128)
#define USE_BUF 1
#endif
#endif
#ifndef USE_BUF
#define USE_BUF 0
#endif

struct XtBuf {
#if USE_BUF
  __amdgpu_buffer_rsrc_t r;
#else
  const char* p;
#endif
};

static __device__ inline XtBuf mkbuf(const ushort_t* xt) {
  XtBuf b;
#if USE_BUF
  b.r = __builtin_amdgcn_make_buffer_rsrc((void*)xt, (short)0, 8388608, 0x00020000);
#else
  b.p = (const char*)xt;
#endif
  return b;
}

// plain (cached) gather load -- NT experiment of round 5 regressed: the
// gather stream has real L1/L2 reuse (FETCH 31->92 MB with NT).
static __device__ inline uint4v xload4(const XtBuf& b, unsigned voff) {
#if USE_BUF
  return __builtin_amdgcn_raw_buffer_load_b128(b.r, (int)voff, 0, 0);
#else
  return *(const uint4v*)(b.p + voff);
#endif
}

// ws layout (floats):
//   xt     : [5308416, +2097152)    x -> [t][h][w][c] f16 (4194304 ushorts)
//   wfrag  : [7405568, +55296)      deform weight B-frags, 110592 f16
//   w2frag : [7460864, +82944)      offconv weight B-frags, 165888 f16

// Merged: blocks [0,1024) transpose x -> xt; blocks [1024,1672) weight prep.
__global__ __launch_bounds__(256) void prep_transpose(
    const float* __restrict__ x, ushort_t* __restrict__ xt,
    const float* __restrict__ offset_w,
    const float* __restrict__ weight,
    ushort_t* __restrict__ w2frag,
    ushort_t* __restrict__ wfrag)
{
  __shared__ float tile[64][65];
  if (blockIdx.x < 1024) {
    int b = blockIdx.x;
    int wblk = b & 1;
    int th = b >> 1;
    int h = th & 127;
    int t = th >> 7;
    int w0 = wblk * 64;
    int lane = threadIdx.x & 63;
    int quad = threadIdx.x >> 6;
    #pragma unroll
    for (int cc = 0; cc < 16; ++cc) {
      int c = cc * 4 + quad;
      tile[c][lane] = x[t * CHW_ + c * HW_ + h * Ww + w0 + lane];
    }
    __syncthreads();
    #pragma unroll
    for (int ww = 0; ww < 16; ++ww) {
      int w = ww * 4 + quad;
      xt[(size_t)(t * HW_ + h * Ww + w0 + w) * 64 + lane] = f2h(tile[lane][w]);
    }
  } else {
    int e = (blockIdx.x - 1024) * 256 + threadIdx.x;
    if (e < 165888) {   // offconv: 27 taps x 6 oc-tiles x 2 khalf x 64 lanes x 8
      int j = e & 7, ln = (e >> 3) & 63, kh2 = (e >> 9) & 1, r = e >> 10;
      int ot = r % 6, k = r / 6;
      int oc = ot * 16 + (ln & 15);
      int c  = kh2 * 32 + (ln >> 4) * 8 + j;
      float v = (oc < 81) ? offset_w[(oc * 64 + c) * 27 + k] : 0.f;
      w2frag[e] = f2h(v);
    }
    if (e < 110592) {   // deform: 27 taps x 4 oc-tiles x 2 khalf x 64 lanes x 8
      int j = e & 7, ln = (e >> 3) & 63, kh2 = (e >> 9) & 1, r = e >> 10;
      int ot = r & 3, k = r >> 2;
      int o = ot * 16 + (ln & 15);
      int c = kh2 * 32 + (ln >> 4) * 8 + j;
      wfrag[e] = f2h(weight[(o * 64 + c) * 27 + k]);
    }
  }
}

// One trilinear site: data chunk (uint4v = 8 f16 ch) x packed weight, into
// even/odd f16x2 accumulator chains (bit-identical order to the 107us kernel).
#define SITE(W, D, A0, A1, A2, A3) \
  { U32H2 wu; wu.u = (W); U32H2 q0, q1, q2, q3; \
    q0.u = (D)[0]; q1.u = (D)[1]; q2.u = (D)[2]; q3.u = (D)[3]; \
    A0 += wu.h * q0.h; A1 += wu.h * q1.h; A2 += wu.h * q2.h; A3 += wu.h * q3.h; }

// Fused offset-conv + deformable conv. One block = 4 waves = 64 positions.
// Round-8 fix: vmcnt ordering. vmcnt retires in issue order, so consuming a
// load issued AFTER the gather prefetch drains the whole pipeline (hidden
// vmcnt(0) per tap in rounds 0-7: weight-frag loads sat behind the gathers).
// New per-iteration VMEM order: [W_k weight frags] -> [consume G(k) /
// issue G(k+1)] -> [MFMA from W regs]. All steady-state waits are
// vmcnt(12/16); the gather window survives the MFMA section.
__global__ __launch_bounds__(256, 4) void fused(
    const float* __restrict__ x,
    const ushort_t* __restrict__ xt,
    const ushort_t* __restrict__ w2frag,
    const float* __restrict__ ob,
    const ushort_t* __restrict__ wfrag,
    const float* __restrict__ gamma,
    float* __restrict__ out)
{
  __shared__ __align__(16) char lds[34372];
  ushort_t* S = (ushort_t*)lds;               // [64 pos][72 f16] = 9216
  unsigned* pm0 = (unsigned*)(lds + 9216);    // [64 pos][8] u32 packed (tap even)
  unsigned* pm1 = (unsigned*)(lds + 11264);   // [64 pos][8] u32 packed (tap odd)
  float* Obuf = (float*)(lds + 13312);        // [81 oc][65] f32 = 21060
  float* Dbuf = (float*)lds;                  // [64 oc][65] f32 (epilogue alias)
  int lane = threadIdx.x & 63;
  int wavei = __builtin_amdgcn_readfirstlane(threadIdx.x >> 6);
  int quad = lane >> 4;
  int m16 = lane & 15;
  int g8 = lane >> 3;
  unsigned coff = (unsigned)((lane & 7) * 16);
  int bid0 = blockIdx.x;
  int p0 = ((bid0 & 7) * 128 + (bid0 >> 3)) * 64;   // XCD swizzle (1024 % 8 == 0)
  int t = p0 >> 14;
  int h = (p0 >> 7) & 127;
  int w0 = p0 & 127;
  XtBuf xb = mkbuf(xt);

  // ---------------- Phase 1: offset conv ----------------
  {
    floatx4 acc[6];
    #pragma unroll
    for (int i = 0; i < 6; ++i) acc[i] = (floatx4){0.f, 0.f, 0.f, 0.f};

    uint4v pd[2];
    f16x8 wva[6], wvb[6];

    auto issue = [&](int k) {
      int kt = k / 9, kh = (k / 3) % 3, kw = k % 3;
      int ts = t + kt - 1, hs = h + kh - 1;
      int tsc = min(max(ts, 0), 3);
      int hsc = min(max(hs, 0), 127);
      int sbase = tsc * HW_ + hsc * Ww;
      #pragma unroll
      for (int b = 0; b < 2; ++b) {
        int prow = wavei * 16 + b * 8 + g8;
        int wc = w0 + prow + kw - 1;
        int wcc = min(max(wc, 0), 127);
        pd[b] = xload4(xb, ((unsigned)(sbase + wcc) << 7) + coff);
      }
    };

    issue(0);
    #pragma unroll 1
    for (int k = 0; k < NT; ++k) {
      // --- W2_k preload FIRST (oldest in vmcnt queue this iteration)
      {
        const ushort_t* wb = w2frag + (size_t)(k * 6) * 1024 + lane * 8;
        #pragma unroll
        for (int ot = 0; ot < 6; ++ot) {
          wva[ot] = *(const f16x8*)(wb + ot * 1024);
          wvb[ot] = *(const f16x8*)(wb + ot * 1024 + 512);
        }
      }
      __builtin_amdgcn_sched_barrier(0);
      int kt = k / 9, kh = (k / 3) % 3, kw = k % 3;
      int ts = t + kt - 1, hs = h + kh - 1;
      bool rowok = ((unsigned)ts < 4u) && ((unsigned)hs < 128u);
      // consume G(k) (oldest): write to S masked -> vmcnt(12), W2 stays in flight
      #pragma unroll
      for (int b = 0; b < 2; ++b) {
        int prow = wavei * 16 + b * 8 + g8;
        int wc = w0 + prow + kw - 1;
        bool ok = rowok && ((unsigned)wc < 128u);
        uint4v v = pd[b];
        if (!ok) v = (uint4v){0u, 0u, 0u, 0u};
        *(uint4v*)((char*)S + prow * 144 + coff) = v;
      }
      if (k + 1 < NT) issue(k + 1);   // G(k+1): youngest
      __builtin_amdgcn_sched_barrier(0);
      // MFMA consumes W2_k (older than G(k+1)) -> vmcnt(2), prefetch survives
      const ushort_t* srow = S + (wavei * 16 + m16) * 72 + quad * 8;
      f16x8 af0 = *(const f16x8*)srow;
      f16x8 af1 = *(const f16x8*)(srow + 32);
      #pragma unroll
      for (int ot = 0; ot < 6; ++ot) {
        acc[ot] = __builtin_amdgcn_mfma_f32_16x16x32_f16(af0, wva[ot], acc[ot], 0, 0, 0);
        acc[ot] = __builtin_amdgcn_mfma_f32_16x16x32_f16(af1, wvb[ot], acc[ot], 0, 0, 0);
      }
    }
    // accumulators -> Obuf (+bias); intra-wave (own 16 positions only)
    #pragma unroll
    for (int ot = 0; ot < 6; ++ot) {
      int oc = ot * 16 + m16;
      if (oc < 81) {
        float bv = ob[oc];
        #pragma unroll
        for (int r = 0; r < 4; ++r)
          Obuf[oc * 65 + wavei * 16 + quad * 4 + r] = acc[ot][r] + bv;
      }
    }
  }

  // ---------------- Phase 2: deform ----------------
  floatx4 acc[4];
  #pragma unroll
  for (int i = 0; i < 4; ++i) acc[i] = (floatx4){0.f, 0.f, 0.f, 0.f};

  int pl = wavei * 16 + m16;
  int aq = quad >> 1, bq = quad & 1;
  int rowA = wavei * 16 + g8;
  int rowB = rowA + 8;

  uint4v stage[16];        // slot-recycled register staging (64 VGPRs)
  f16x8 wva[4], wvb[4];    // per-tap deform weight frags (32 VGPRs)

  auto meta = [&](int kk, float dtv, float dhv, float dwv) {
    unsigned* pm = (kk & 1) ? pm1 : pm0;
    int kt = kk / 9, kh = (kk / 3) % 3, kw = kk % 3;
    float tf = (float)(t + kt - 1) + dtv;
    float hf = (float)(h + kh - 1) + dhv;
    float wf = (float)(w0 + pl + kw - 1) + dwv;
    float tF = floorf(tf), hF = floorf(hf), wF = floorf(wf);
    float lt = tf - tF, lh_ = hf - hF, lw_ = wf - wF;
    int t0 = (int)tF, h0 = (int)hF, wq_ = (int)wF;
    int ti = t0 + aq;
    float wt_ = (aq ? lt : 1.f - lt) * (((unsigned)ti < 4u) ? 1.f : 0.f);
    int tic = min(max(ti, 0), 3);
    int hi = h0 + bq;
    float wh_ = (bq ? lh_ : 1.f - lh_) * (((unsigned)hi < 128u) ? 1.f : 0.f);
    int hic = min(max(hi, 0), 127);
    int base2 = tic * HW_ + hic * Ww;
    float bw = wt_ * wh_;
    int wi0 = wq_;
    float ww0 = (1.f - lw_) * (((unsigned)wi0 < 128u) ? 1.f : 0.f);
    int wi0c = min(max(wi0, 0), 127);
    int wi1 = wq_ + 1;
    float ww1 = lw_ * (((unsigned)wi1 < 128u) ? 1.f : 0.f);
    int wi1c = min(max(wi1, 0), 127);
    uint2 mp_;
    mp_.x = ((unsigned)(base2 + wi0c) << 16) | (pk2(bw * ww0) & 0xFFFFu);
    mp_.y = ((unsigned)(base2 + wi1c) << 16) | (pk2(bw * ww1) & 0xFFFFu);
    *(uint2*)&pm[pl * 8 + quad * 2] = mp_;
  };

  // voff from packed word: (site<<7) + coff
  auto vof = [&](unsigned p) -> unsigned {
    return ((p >> 9) & 0xFFFFFF80u) + coff;
  };

  // consume tap kk's half, weights from pmeta[kk&1]; reissue same slots for
  // tap kk+1 (sites from pmeta[(kk+1)&1]).
  auto halfA = [&](int kk, bool more) {
    const unsigned* pmc = (kk & 1) ? pm1 : pm0;
    const uint4* wp = (const uint4*)&pmc[rowA * 8];
    uint4 w03 = wp[0], w47 = wp[1];
    U32H2 z; z.u = 0;
    f16x2 e0 = z.h, e1 = z.h, e2 = z.h, e3 = z.h;
    f16x2 o0 = z.h, o1 = z.h, o2 = z.h, o3 = z.h;
    SITE(rep16(w03.x), stage[0], e0, e1, e2, e3)
    SITE(rep16(w03.y), stage[1], o0, o1, o2, o3)
    SITE(rep16(w03.z), stage[2], e0, e1, e2, e3)
    SITE(rep16(w03.w), stage[3], o0, o1, o2, o3)
    SITE(rep16(w47.x), stage[4], e0, e1, e2, e3)
    SITE(rep16(w47.y), stage[5], o0, o1, o2, o3)
    SITE(rep16(w47.z), stage[6], e0, e1, e2, e3)
    SITE(rep16(w47.w), stage[7], o0, o1, o2, o3)
    U32H2 r0, r1, r2, r3;
    r0.h = e0 + o0; r1.h = e1 + o1; r2.h = e2 + o2; r3.h = e3 + o3;
    uint4v res = {r0.u, r1.u, r2.u, r3.u};
    *(uint4v*)((char*)S + rowA * 144 + coff) = res;
    if (more) {
      const unsigned* pmn = (kk & 1) ? pm0 : pm1;
      const uint4* sp = (const uint4*)&pmn[rowA * 8];
      uint4 s0 = sp[0], s1 = sp[1];
      stage[0] = xload4(xb, vof(s0.x));
      stage[1] = xload4(xb, vof(s0.y));
      stage[2] = xload4(xb, vof(s0.z));
      stage[3] = xload4(xb, vof(s0.w));
      stage[4] = xload4(xb, vof(s1.x));
      stage[5] = xload4(xb, vof(s1.y));
      stage[6] = xload4(xb, vof(s1.z));
      stage[7] = xload4(xb, vof(s1.w));
    }
  };
  auto halfB = [&](int kk, bool more) {
    const unsigned* pmc = (kk & 1) ? pm1 : pm0;
    const uint4* wp = (const uint4*)&pmc[rowB * 8];
    uint4 w03 = wp[0], w47 = wp[1];
    U32H2 z; z.u = 0;
    f16x2 e0 = z.h, e1 = z.h, e2 = z.h, e3 = z.h;
    f16x2 o0 = z.h, o1 = z.h, o2 = z.h, o3 = z.h;
    SITE(rep16(w03.x), stage[8],  e0, e1, e2, e3)
    SITE(rep16(w03.y), stage[9],  o0, o1, o2, o3)
    SITE(rep16(w03.z), stage[10], e0, e1, e2, e3)
    SITE(rep16(w03.w), stage[11], o0, o1, o2, o3)
    SITE(rep16(w47.x), stage[12], e0, e1, e2, e3)
    SITE(rep16(w47.y), stage[13], o0, o1, o2, o3)
    SITE(rep16(w47.z), stage[14], e0, e1, e2, e3)
    SITE(rep16(w47.w), stage[15], o0, o1, o2, o3)
    U32H2 r0, r1, r2, r3;
    r0.h = e0 + o0; r1.h = e1 + o1; r2.h = e2 + o2; r3.h = e3 + o3;
    uint4v res = {r0.u, r1.u, r2.u, r3.u};
    *(uint4v*)((char*)S + rowB * 144 + coff) = res;
    if (more) {
      const unsigned* pmn = (kk & 1) ? pm0 : pm1;
      const uint4* sp = (const uint4*)&pmn[rowB * 8];
      uint4 s0 = sp[0], s1 = sp[1];
      stage[8]  = xload4(xb, vof(s0.x));
      stage[9]  = xload4(xb, vof(s0.y));
      stage[10] = xload4(xb, vof(s0.z));
      stage[11] = xload4(xb, vof(s0.w));
      stage[12] = xload4(xb, vof(s1.x));
      stage[13] = xload4(xb, vof(s1.y));
      stage[14] = xload4(xb, vof(s1.z));
      stage[15] = xload4(xb, vof(s1.w));
    }
  };

  // prologue: meta(0) -> issue tap 0 (both halves)
  {
    float dt0 = Obuf[(0 * NT + 0) * 65 + pl];
    float dh0 = Obuf[(1 * NT + 0) * 65 + pl];
    float dw0 = Obuf[(2 * NT + 0) * 65 + pl];
    meta(0, dt0, dh0, dw0);
  }
  {
    const uint4* spA = (const uint4*)&pm0[rowA * 8];
    uint4 a0 = spA[0], a1 = spA[1];
    stage[0] = xload4(xb, vof(a0.x));
    stage[1] = xload4(xb, vof(a0.y));
    stage[2] = xload4(xb, vof(a0.z));
    stage[3] = xload4(xb, vof(a0.w));
    stage[4] = xload4(xb, vof(a1.x));
    stage[5] = xload4(xb, vof(a1.y));
    stage[6] = xload4(xb, vof(a1.z));
    stage[7] = xload4(xb, vof(a1.w));
    const uint4* spB = (const uint4*)&pm0[rowB * 8];
    uint4 b0 = spB[0], b1 = spB[1];
    stage[8]  = xload4(xb, vof(b0.x));
    stage[9]  = xload4(xb, vof(b0.y));
    stage[10] = xload4(xb, vof(b0.z));
    stage[11] = xload4(xb, vof(b0.w));
    stage[12] = xload4(xb, vof(b1.x));
    stage[13] = xload4(xb, vof(b1.y));
    stage[14] = xload4(xb, vof(b1.z));
    stage[15] = xload4(xb, vof(b1.w));
  }

  #pragma unroll 1
  for (int k = 0; k < NT; ++k) {
    bool more = (k + 1 < NT);
    // --- W_k preload FIRST (oldest in this iteration's vmcnt queue)
    {
      const ushort_t* wb = wfrag + (size_t)(k * 4) * 1024 + lane * 8;
      #pragma unroll
      for (int ot = 0; ot < 4; ++ot) {
        wva[ot] = *(const f16x8*)(wb + ot * 1024);
        wvb[ot] = *(const f16x8*)(wb + ot * 1024 + 512);
      }
    }
    __builtin_amdgcn_sched_barrier(0);
    // meta for tap k+1 (full tap ahead) -> pmeta[(k+1)&1]
    if (more) {
      float dt_n = Obuf[(0 * NT + (k + 1)) * 65 + pl];
      float dh_n = Obuf[(1 * NT + (k + 1)) * 65 + pl];
      float dw_n = Obuf[(2 * NT + (k + 1)) * 65 + pl];
      meta(k + 1, dt_n, dh_n, dw_n);
    }
    __builtin_amdgcn_sched_barrier(0);
    halfA(k, more);    // consume G_A(k) (oldest) -> vmcnt(16); reissue
    __builtin_amdgcn_sched_barrier(0);
    halfB(k, more);    // consume G_B(k) (oldest) -> vmcnt(16); reissue
    __builtin_amdgcn_sched_barrier(0);

    // --- MFMA tap k: consumes W_k (older than G(k+1)) -> vmcnt(16)
    const ushort_t* srow = S + (wavei * 16 + m16) * 72 + quad * 8;
    f16x8 af0 = *(const f16x8*)srow;
    f16x8 af1 = *(const f16x8*)(srow + 32);
    #pragma unroll
    for (int ot = 0; ot < 4; ++ot) {
      acc[ot] = __builtin_amdgcn_mfma_f32_16x16x32_f16(af0, wva[ot], acc[ot], 0, 0, 0);
      acc[ot] = __builtin_amdgcn_mfma_f32_16x16x32_f16(af1, wvb[ot], acc[ot], 0, 0, 0);
    }
  }
  __syncthreads();   // S/pmeta/Obuf dead; Dbuf aliases them
  #pragma unroll
  for (int ot = 0; ot < 4; ++ot)
    #pragma unroll
    for (int r = 0; r < 4; ++r)
      Dbuf[(ot * 16 + m16) * 65 + wavei * 16 + quad * 4 + r] = acc[ot][r];
  __syncthreads();
  float g = gamma[0];
  for (int i = threadIdx.x; i < 64 * 64; i += 256) {
    int oc = i >> 6, p = i & 63;
    size_t oi = (size_t)t * CHW_ + (size_t)oc * HW_ + (size_t)h * Ww + w0 + p;
    out[oi] = fmaf(g, Dbuf[oc * 65 + p], x[oi]);
  }
}

extern "C" void kernel_launch(void* const* d_in, const int* in_sizes, int n_in,
                              void* d_out, int out_size, void* d_ws, size_t ws_size,
                              hipStream_t stream) {
  (void)in_sizes; (void)n_in; (void)out_size; (void)ws_size;
  const float* x        = (const float*)d_in[0];
  const float* offset_w = (const float*)d_in[1];
  const float* offset_b = (const float*)d_in[2];
  const float* weight   = (const float*)d_in[3];
  const float* gamma    = (const float*)d_in[4];
  float* out = (float*)d_out;
  float* wsf = (float*)d_ws;
  ushort_t* xt     = (ushort_t*)(wsf + 5308416);        // 4194304 f16
  ushort_t* wfrag  = (ushort_t*)(wsf + 7405568);        // 110592 f16
  ushort_t* w2frag = (ushort_t*)(wsf + 7460864);        // 165888 f16

  hipLaunchKernelGGL(prep_transpose, dim3(1672), dim3(256), 0, stream,
                     x, xt, offset_w, weight, w2frag, wfrag);
  hipLaunchKernelGGL(fused, dim3(1024), dim3(256), 0, stream,
                     x, xt, w2frag, offset_b, wfrag, gamma, out);
}

// Round 9
// 199.102 us; speedup vs baseline: 1.3243x; 1.3243x over previous
//
#include <hip/hip_runtime.h>
#include <cmath>

// Problem constants (B=1): x (1,4,64,128,128) f32
#define Cc 64
#define Hh 128
#define Ww 128
#define HW_ 16384
#define THW_ 65536
#define CHW_ 1048576
#define NT 27

typedef unsigned short ushort_t;
typedef _Float16 f16x2 __attribute__((ext_vector_type(2)));
typedef _Float16 f16x8 __attribute__((ext_vector_type(8)));
typedef __fp16 fp16x2_alt __attribute__((ext_vector_type(2)));
typedef float floatx4 __attribute__((ext_vector_type(4)));
typedef unsigned uint4v __attribute__((ext_vector_type(4)));

union U32H2 { unsigned u; f16x2 h; };

static __device__ inline ushort_t f2h(float f) {
  union { _Float16 h; ushort_t u; } v;
  v.h = (_Float16)f;
  return v.u;
}

static __device__ inline unsigned pk2(float a) {
  union { fp16x2_alt h; unsigned u; } v;
  v.h = __builtin_amdgcn_cvt_pkrtz(a, a);
  return v.u;
}

// replicate low 16 bits into both halves (weight broadcast for f16x2 math)
static __device__ inline unsigned rep16(unsigned p) {
#if defined(__has_builtin)
#if __has_builtin(__builtin_amdgcn_perm)
  return __builtin_amdgcn_perm(p, p, 0x01000100u);
#else
  return (p & 0xFFFFu) * 0x10001u;
#endif
#else
  return (p & 0xFFFFu) * 0x10001u;
#endif
}

#if defined(__has_builtin)
#if __has_builtin(__builtin_amdgcn_make_buffer_rsrc) && __has_builtin(__builtin_amdgcn_raw_buffer_load_b32) && __has_builtin(__builtin_amdgcn_raw_buffer_load_b128)
#define USE_BUF 1
#endif
#endif
#ifndef USE_BUF
#define USE_BUF 0
#endif

struct XtBuf {
#if USE_BUF
  __amdgpu_buffer_rsrc_t r;
#else
  const char* p;
#endif
};

static __device__ inline XtBuf mkbuf(const ushort_t* xt) {
  XtBuf b;
#if USE_BUF
  b.r = __builtin_amdgcn_make_buffer_rsrc((void*)xt, (short)0, 8388608, 0x00020000);
#else
  b.p = (const char*)xt;
#endif
  return b;
}

static __device__ inline uint4v xload4(const XtBuf& b, unsigned voff) {
#if USE_BUF
  return __builtin_amdgcn_raw_buffer_load_b128(b.r, (int)voff, 0, 0);
#else
  return *(const uint4v*)(b.p + voff);
#endif
}

// ws layout (floats):
//   xt     : [5308416, +2097152)    x -> [t][h][w][c] f16 (4194304 ushorts)
//   wfrag  : [7405568, +55296)      deform weight B-frags, 110592 f16
//   w2frag : [7460864, +82944)      offconv weight B-frags, 165888 f16

// Merged: blocks [0,1024) transpose x -> xt; blocks [1024,1672) weight prep.
__global__ __launch_bounds__(256) void prep_transpose(
    const float* __restrict__ x, ushort_t* __restrict__ xt,
    const float* __restrict__ offset_w,
    const float* __restrict__ weight,
    ushort_t* __restrict__ w2frag,
    ushort_t* __restrict__ wfrag)
{
  __shared__ float tile[64][65];
  if (blockIdx.x < 1024) {
    int b = blockIdx.x;
    int wblk = b & 1;
    int th = b >> 1;
    int h = th & 127;
    int t = th >> 7;
    int w0 = wblk * 64;
    int lane = threadIdx.x & 63;
    int quad = threadIdx.x >> 6;
    #pragma unroll
    for (int cc = 0; cc < 16; ++cc) {
      int c = cc * 4 + quad;
      tile[c][lane] = x[t * CHW_ + c * HW_ + h * Ww + w0 + lane];
    }
    __syncthreads();
    #pragma unroll
    for (int ww = 0; ww < 16; ++ww) {
      int w = ww * 4 + quad;
      xt[(size_t)(t * HW_ + h * Ww + w0 + w) * 64 + lane] = f2h(tile[lane][w]);
    }
  } else {
    int e = (blockIdx.x - 1024) * 256 + threadIdx.x;
    if (e < 165888) {   // offconv: 27 taps x 6 oc-tiles x 2 khalf x 64 lanes x 8
      int j = e & 7, ln = (e >> 3) & 63, kh2 = (e >> 9) & 1, r = e >> 10;
      int ot = r % 6, k = r / 6;
      int oc = ot * 16 + (ln & 15);
      int c  = kh2 * 32 + (ln >> 4) * 8 + j;
      float v = (oc < 81) ? offset_w[(oc * 64 + c) * 27 + k] : 0.f;
      w2frag[e] = f2h(v);
    }
    if (e < 110592) {   // deform: 27 taps x 4 oc-tiles x 2 khalf x 64 lanes x 8
      int j = e & 7, ln = (e >> 3) & 63, kh2 = (e >> 9) & 1, r = e >> 10;
      int ot = r & 3, k = r >> 2;
      int o = ot * 16 + (ln & 15);
      int c = kh2 * 32 + (ln >> 4) * 8 + j;
      wfrag[e] = f2h(weight[(o * 64 + c) * 27 + k]);
    }
  }
}

// One trilinear site: data chunk (uint4v = 8 f16 ch) x packed weight, into
// even/odd f16x2 accumulator chains (bit-identical order to the 107us kernel).
#define SITE(W, D, A0, A1, A2, A3) \
  { U32H2 wu; wu.u = (W); U32H2 q0, q1, q2, q3; \
    q0.u = (D)[0]; q1.u = (D)[1]; q2.u = (D)[2]; q3.u = (D)[3]; \
    A0 += wu.h * q0.h; A1 += wu.h * q1.h; A2 += wu.h * q2.h; A3 += wu.h * q3.h; }

// Fused offset-conv + deformable conv. One block = 4 waves = 64 positions.
// Round-9 change: the kernel is ~75% of a per-CU VMEM-pipe roofline (each
// 1KB wave load ~16cy at 64B/cy L1 path; weight loads alone are ~half the
// pipe time and are 4x-redundant across the block's waves). Weight fragments
// are now staged into LDS once per block per tap (cooperative loads) and read
// via ds_read_b128 (separate LDS pipe, short-lived regs -> no spill; r8's
// register preload spilled). Barriers are scheduled so NO VMEM is outstanding
// at any barrier (wreg drained by its ds_write; gathers consumed before /
// issued after) -- the compiler's vmcnt(0)-before-s_barrier drain is a no-op.
// LDS 50.8KB -> 3 blocks/CU; (256,3) raises the VGPR cap to ~168.
__global__ __launch_bounds__(256, 3) void fused(
    const float* __restrict__ x,
    const ushort_t* __restrict__ xt,
    const ushort_t* __restrict__ w2frag,
    const float* __restrict__ ob,
    const ushort_t* __restrict__ wfrag,
    const float* __restrict__ gamma,
    float* __restrict__ out)
{
  __shared__ __align__(16) char lds[50768];
  ushort_t* S = (ushort_t*)lds;               // [64 pos][72 f16] = 9216
  unsigned* pm0 = (unsigned*)(lds + 9216);    // [64 pos][8] u32 packed (tap even)
  unsigned* pm1 = (unsigned*)(lds + 11264);   // [64 pos][8] u32 packed (tap odd)
  ushort_t* W2lds = (ushort_t*)(lds + 9216);  // phase1 weight slice, 12288 B (aliases pm+Wl0 head)
  ushort_t* Wl0 = (ushort_t*)(lds + 13312);   // phase2 weight dbuf A, 8192 B
  ushort_t* Wl1 = (ushort_t*)(lds + 21504);   // phase2 weight dbuf B, 8192 B
  float* Obuf = (float*)(lds + 29696);        // [81 oc][65] f32 = 21060
  float* Dbuf = (float*)lds;                  // [64 oc][65] f32 (epilogue alias)
  int tid = threadIdx.x;
  int lane = tid & 63;
  int wavei = __builtin_amdgcn_readfirstlane(tid >> 6);
  int quad = lane >> 4;
  int m16 = lane & 15;
  int g8 = lane >> 3;
  unsigned coff = (unsigned)((lane & 7) * 16);
  int bid0 = blockIdx.x;
  int p0 = ((bid0 & 7) * 128 + (bid0 >> 3)) * 64;   // XCD swizzle (1024 % 8 == 0)
  int t = p0 >> 14;
  int h = (p0 >> 7) & 127;
  int w0 = p0 & 127;
  XtBuf xb = mkbuf(xt);

  // ---------------- Phase 1: offset conv ----------------
  {
    floatx4 acc[6];
    #pragma unroll
    for (int i = 0; i < 6; ++i) acc[i] = (floatx4){0.f, 0.f, 0.f, 0.f};

    uint4v pd[2];
    uint4v w2reg[3];

    auto issue = [&](int k) {
      int kt = k / 9, kh = (k / 3) % 3, kw = k % 3;
      int ts = t + kt - 1, hs = h + kh - 1;
      int tsc = min(max(ts, 0), 3);
      int hsc = min(max(hs, 0), 127);
      int sbase = tsc * HW_ + hsc * Ww;
      #pragma unroll
      for (int b = 0; b < 2; ++b) {
        int prow = wavei * 16 + b * 8 + g8;
        int wc = w0 + prow + kw - 1;
        int wcc = min(max(wc, 0), 127);
        pd[b] = xload4(xb, ((unsigned)(sbase + wcc) << 7) + coff);
      }
    };
    auto wload = [&](int k) {   // cooperative: 3 x 16B per thread
      const uint4v* src = (const uint4v*)(w2frag + (size_t)k * 6144);
      #pragma unroll
      for (int c = 0; c < 3; ++c) w2reg[c] = src[tid + c * 256];
    };
    auto wstore = [&]() {
      uint4v* dst = (uint4v*)W2lds;
      #pragma unroll
      for (int c = 0; c < 3; ++c) dst[tid + c * 256] = w2reg[c];
    };

    wload(0);
    wstore();
    __syncthreads();           // W2lds[0] visible
    issue(0);

    #pragma unroll 1
    for (int k = 0; k < NT; ++k) {
      bool more = (k + 1 < NT);
      if (more) wload(k + 1);                 // VMEM: oldest this iteration
      __builtin_amdgcn_sched_barrier(0);
      // tap-k weight fragments from LDS (short-lived regs)
      f16x8 wva[6], wvb[6];
      #pragma unroll
      for (int ot = 0; ot < 6; ++ot) {
        wva[ot] = *(const f16x8*)(W2lds + ot * 1024 + lane * 8);
        wvb[ot] = *(const f16x8*)(W2lds + ot * 1024 + 512 + lane * 8);
      }
      // consume G(k) -> S (masked)
      int kt = k / 9, kh = (k / 3) % 3, kw = k % 3;
      int ts = t + kt - 1, hs = h + kh - 1;
      bool rowok = ((unsigned)ts < 4u) && ((unsigned)hs < 128u);
      #pragma unroll
      for (int b = 0; b < 2; ++b) {
        int prow = wavei * 16 + b * 8 + g8;
        int wc = w0 + prow + kw - 1;
        bool ok = rowok && ((unsigned)wc < 128u);
        uint4v v = pd[b];
        if (!ok) v = (uint4v){0u, 0u, 0u, 0u};
        *(uint4v*)((char*)S + prow * 144 + coff) = v;
      }
      __builtin_amdgcn_sched_barrier(0);
      // MFMA tap k
      const ushort_t* srow = S + (wavei * 16 + m16) * 72 + quad * 8;
      f16x8 af0 = *(const f16x8*)srow;
      f16x8 af1 = *(const f16x8*)(srow + 32);
      #pragma unroll
      for (int ot = 0; ot < 6; ++ot) {
        acc[ot] = __builtin_amdgcn_mfma_f32_16x16x32_f16(af0, wva[ot], acc[ot], 0, 0, 0);
        acc[ot] = __builtin_amdgcn_mfma_f32_16x16x32_f16(af1, wvb[ot], acc[ot], 0, 0, 0);
      }
      __syncthreads();           // all waves done reading W2lds[k] (no VMEM outstanding but w2reg; covered)
      if (more) wstore();        // write tap k+1 slice
      __syncthreads();           // visible
      if (more) issue(k + 1);    // gathers issued after barriers: never drained
    }
    // accumulators -> Obuf (+bias); intra-wave (own 16 positions only)
    #pragma unroll
    for (int ot = 0; ot < 6; ++ot) {
      int oc = ot * 16 + m16;
      if (oc < 81) {
        float bv = ob[oc];
        #pragma unroll
        for (int r = 0; r < 4; ++r)
          Obuf[oc * 65 + wavei * 16 + quad * 4 + r] = acc[ot][r] + bv;
      }
    }
  }

  // ---------------- Phase 2: deform ----------------
  floatx4 acc[4];
  #pragma unroll
  for (int i = 0; i < 4; ++i) acc[i] = (floatx4){0.f, 0.f, 0.f, 0.f};

  int pl = wavei * 16 + m16;
  int aq = quad >> 1, bq = quad & 1;
  int rowA = wavei * 16 + g8;
  int rowB = rowA + 8;

  uint4v stage[16];   // full-tap register staging (64 VGPRs)
  uint4v wreg[2];

  auto meta = [&](int kk, float dtv, float dhv, float dwv) {
    unsigned* pm = (kk & 1) ? pm1 : pm0;
    int kt = kk / 9, kh = (kk / 3) % 3, kw = kk % 3;
    float tf = (float)(t + kt - 1) + dtv;
    float hf = (float)(h + kh - 1) + dhv;
    float wf = (float)(w0 + pl + kw - 1) + dwv;
    float tF = floorf(tf), hF = floorf(hf), wF = floorf(wf);
    float lt = tf - tF, lh_ = hf - hF, lw_ = wf - wF;
    int t0 = (int)tF, h0 = (int)hF, wq_ = (int)wF;
    int ti = t0 + aq;
    float wt_ = (aq ? lt : 1.f - lt) * (((unsigned)ti < 4u) ? 1.f : 0.f);
    int tic = min(max(ti, 0), 3);
    int hi = h0 + bq;
    float wh_ = (bq ? lh_ : 1.f - lh_) * (((unsigned)hi < 128u) ? 1.f : 0.f);
    int hic = min(max(hi, 0), 127);
    int base2 = tic * HW_ + hic * Ww;
    float bw = wt_ * wh_;
    int wi0 = wq_;
    float ww0 = (1.f - lw_) * (((unsigned)wi0 < 128u) ? 1.f : 0.f);
    int wi0c = min(max(wi0, 0), 127);
    int wi1 = wq_ + 1;
    float ww1 = lw_ * (((unsigned)wi1 < 128u) ? 1.f : 0.f);
    int wi1c = min(max(wi1, 0), 127);
    uint2 mp_;
    mp_.x = ((unsigned)(base2 + wi0c) << 16) | (pk2(bw * ww0) & 0xFFFFu);
    mp_.y = ((unsigned)(base2 + wi1c) << 16) | (pk2(bw * ww1) & 0xFFFFu);
    *(uint2*)&pm[pl * 8 + quad * 2] = mp_;
  };

  // voff from packed word: (site<<7) + coff
  auto vof = [&](unsigned p) -> unsigned {
    return ((p >> 9) & 0xFFFFFF80u) + coff;
  };

  auto wload2 = [&](int k) {   // cooperative: 2 x 16B per thread
    const uint4v* src = (const uint4v*)(wfrag + (size_t)k * 4096);
    wreg[0] = src[tid];
    wreg[1] = src[tid + 256];
  };
  auto wstore2 = [&](int k) {
    uint4v* dst = (uint4v*)((k & 1) ? Wl1 : Wl0);
    dst[tid] = wreg[0];
    dst[tid + 256] = wreg[1];
  };

  auto issueAll = [&](int kk) {   // all 16 gathers of tap kk into stage
    const unsigned* pmn = (kk & 1) ? pm1 : pm0;
    const uint4* spA = (const uint4*)&pmn[rowA * 8];
    uint4 a0 = spA[0], a1 = spA[1];
    const uint4* spB = (const uint4*)&pmn[rowB * 8];
    uint4 b0 = spB[0], b1 = spB[1];
    stage[0]  = xload4(xb, vof(a0.x));
    stage[1]  = xload4(xb, vof(a0.y));
    stage[2]  = xload4(xb, vof(a0.z));
    stage[3]  = xload4(xb, vof(a0.w));
    stage[4]  = xload4(xb, vof(a1.x));
    stage[5]  = xload4(xb, vof(a1.y));
    stage[6]  = xload4(xb, vof(a1.z));
    stage[7]  = xload4(xb, vof(a1.w));
    stage[8]  = xload4(xb, vof(b0.x));
    stage[9]  = xload4(xb, vof(b0.y));
    stage[10] = xload4(xb, vof(b0.z));
    stage[11] = xload4(xb, vof(b0.w));
    stage[12] = xload4(xb, vof(b1.x));
    stage[13] = xload4(xb, vof(b1.y));
    stage[14] = xload4(xb, vof(b1.z));
    stage[15] = xload4(xb, vof(b1.w));
  };

  auto consumeA = [&](int kk) {
    const unsigned* pmc = (kk & 1) ? pm1 : pm0;
    const uint4* wp = (const uint4*)&pmc[rowA * 8];
    uint4 w03 = wp[0], w47 = wp[1];
    U32H2 z; z.u = 0;
    f16x2 e0 = z.h, e1 = z.h, e2 = z.h, e3 = z.h;
    f16x2 o0 = z.h, o1 = z.h, o2 = z.h, o3 = z.h;
    SITE(rep16(w03.x), stage[0], e0, e1, e2, e3)
    SITE(rep16(w03.y), stage[1], o0, o1, o2, o3)
    SITE(rep16(w03.z), stage[2], e0, e1, e2, e3)
    SITE(rep16(w03.w), stage[3], o0, o1, o2, o3)
    SITE(rep16(w47.x), stage[4], e0, e1, e2, e3)
    SITE(rep16(w47.y), stage[5], o0, o1, o2, o3)
    SITE(rep16(w47.z), stage[6], e0, e1, e2, e3)
    SITE(rep16(w47.w), stage[7], o0, o1, o2, o3)
    U32H2 r0, r1, r2, r3;
    r0.h = e0 + o0; r1.h = e1 + o1; r2.h = e2 + o2; r3.h = e3 + o3;
    uint4v res = {r0.u, r1.u, r2.u, r3.u};
    *(uint4v*)((char*)S + rowA * 144 + coff) = res;
  };
  auto consumeB = [&](int kk) {
    const unsigned* pmc = (kk & 1) ? pm1 : pm0;
    const uint4* wp = (const uint4*)&pmc[rowB * 8];
    uint4 w03 = wp[0], w47 = wp[1];
    U32H2 z; z.u = 0;
    f16x2 e0 = z.h, e1 = z.h, e2 = z.h, e3 = z.h;
    f16x2 o0 = z.h, o1 = z.h, o2 = z.h, o3 = z.h;
    SITE(rep16(w03.x), stage[8],  e0, e1, e2, e3)
    SITE(rep16(w03.y), stage[9],  o0, o1, o2, o3)
    SITE(rep16(w03.z), stage[10], e0, e1, e2, e3)
    SITE(rep16(w03.w), stage[11], o0, o1, o2, o3)
    SITE(rep16(w47.x), stage[12], e0, e1, e2, e3)
    SITE(rep16(w47.y), stage[13], o0, o1, o2, o3)
    SITE(rep16(w47.z), stage[14], e0, e1, e2, e3)
    SITE(rep16(w47.w), stage[15], o0, o1, o2, o3)
    U32H2 r0, r1, r2, r3;
    r0.h = e0 + o0; r1.h = e1 + o1; r2.h = e2 + o2; r3.h = e3 + o3;
    uint4v res = {r0.u, r1.u, r2.u, r3.u};
    *(uint4v*)((char*)S + rowB * 144 + coff) = res;
  };

  // prologue
  __syncthreads();              // inter-phase: W2lds region dead before pm/Wl writes
  wload2(0);
  {
    float dt0 = Obuf[(0 * NT + 0) * 65 + pl];
    float dh0 = Obuf[(1 * NT + 0) * 65 + pl];
    float dw0 = Obuf[(2 * NT + 0) * 65 + pl];
    meta(0, dt0, dh0, dw0);
  }
  wstore2(0);
  __syncthreads();              // Wl0 + pm0 visible
  issueAll(0);

  #pragma unroll 1
  for (int k = 0; k < NT; ++k) {
    bool more = (k + 1 < NT);
    if (more) wload2(k + 1);                   // VMEM: oldest this iteration
    if (more) {
      float dt_n = Obuf[(0 * NT + (k + 1)) * 65 + pl];
      float dh_n = Obuf[(1 * NT + (k + 1)) * 65 + pl];
      float dw_n = Obuf[(2 * NT + (k + 1)) * 65 + pl];
      meta(k + 1, dt_n, dh_n, dw_n);
    }
    __builtin_amdgcn_sched_barrier(0);
    consumeA(k);                               // consumes G(k) (oldest outstanding)
    consumeB(k);
    __builtin_amdgcn_sched_barrier(0);
    // tap-k weight fragments from LDS (short-lived; stage regs are dead here)
    f16x8 wva[4], wvb[4];
    {
      const ushort_t* Wl = (k & 1) ? Wl1 : Wl0;
      #pragma unroll
      for (int ot = 0; ot < 4; ++ot) {
        wva[ot] = *(const f16x8*)(Wl + ot * 1024 + lane * 8);
        wvb[ot] = *(const f16x8*)(Wl + ot * 1024 + 512 + lane * 8);
      }
    }
    if (more) wstore2(k + 1);                  // drains wreg (covered by meta+consume)
    // MFMA tap k
    const ushort_t* srow = S + (wavei * 16 + m16) * 72 + quad * 8;
    f16x8 af0 = *(const f16x8*)srow;
    f16x8 af1 = *(const f16x8*)(srow + 32);
    #pragma unroll
    for (int ot = 0; ot < 4; ++ot) {
      acc[ot] = __builtin_amdgcn_mfma_f32_16x16x32_f16(af0, wva[ot], acc[ot], 0, 0, 0);
      acc[ot] = __builtin_amdgcn_mfma_f32_16x16x32_f16(af1, wvb[ot], acc[ot], 0, 0, 0);
    }
    __syncthreads();                           // Wl[(k+1)&1] visible; NO VMEM outstanding
    if (more) issueAll(k + 1);                 // gathers issued after barrier: never drained
  }
  __syncthreads();   // S/pm/Wl/Obuf dead; Dbuf aliases them
  #pragma unroll
  for (int ot = 0; ot < 4; ++ot)
    #pragma unroll
    for (int r = 0; r < 4; ++r)
      Dbuf[(ot * 16 + m16) * 65 + wavei * 16 + quad * 4 + r] = acc[ot][r];
  __syncthreads();
  float g = gamma[0];
  for (int i = threadIdx.x; i < 64 * 64; i += 256) {
    int oc = i >> 6, p = i & 63;
    size_t oi = (size_t)t * CHW_ + (size_t)oc * HW_ + (size_t)h * Ww + w0 + p;
    out[oi] = fmaf(g, Dbuf[oc * 65 + p], x[oi]);
  }
}

extern "C" void kernel_launch(void* const* d_in, const int* in_sizes, int n_in,
                              void* d_out, int out_size, void* d_ws, size_t ws_size,
                              hipStream_t stream) {
  (void)in_sizes; (void)n_in; (void)out_size; (void)ws_size;
  const float* x        = (const float*)d_in[0];
  const float* offset_w = (const float*)d_in[1];
  const float* offset_b = (const float*)d_in[2];
  const float* weight   = (const float*)d_in[3];
  const float* gamma    = (const float*)d_in[4];
  float* out = (float*)d_out;
  float* wsf = (float*)d_ws;
  ushort_t* xt     = (ushort_t*)(wsf + 5308416);        // 4194304 f16
  ushort_t* wfrag  = (ushort_t*)(wsf + 7405568);        // 110592 f16
  ushort_t* w2frag = (ushort_t*)(wsf + 7460864);        // 165888 f16

  hipLaunchKernelGGL(prep_transpose, dim3(1672), dim3(256), 0, stream,
                     x, xt, offset_w, weight, w2frag, wfrag);
  hipLaunchKernelGGL(fused, dim3(1024), dim3(256), 0, stream,
                     x, xt, w2frag, offset_b, wfrag, gamma, out);
}